// Round 2
// baseline (1439.199 us; speedup 1.0000x reference)
//
#include <hip/hip_runtime.h>

// GCN layer on MI355X.
// out[col] = dis[col] * ( sum_{e: dst=col} t2[row_e] + t2[col] ) + bias
// where t2[i] = dis[i] * (x @ W)[i], dis[i] = 1/sqrt(deg[i]),
// deg[i] = 1 (self loop) + count of i in edge_index[0].
//
// NOTE: harness pushes integer inputs as int32 (edge_index arrives as int*),
// NOT int64 — round-1 crash was long-long misreads -> OOB atomics.

static inline int cdiv(int a, int b) { return (a + b - 1) / b; }

__global__ void k_deg_init(int* __restrict__ deg, int n) {
  int i = blockIdx.x * blockDim.x + threadIdx.x;
  if (i < n) deg[i] = 1;  // self loop contributes 1
}

__global__ void k_deg_count(const int* __restrict__ src, int E, int* __restrict__ deg) {
  int e = blockIdx.x * blockDim.x + threadIdx.x;
  if (e < E) atomicAdd(&deg[src[e]], 1);
}

__global__ void k_dis(const int* __restrict__ deg, float* __restrict__ dis, int n) {
  int i = blockIdx.x * blockDim.x + threadIdx.x;
  if (i < n) dis[i] = rsqrtf((float)deg[i]);
}

// t2[r][c] = dis[r] * sum_k x[r][k] * W[k][c]
// Block 256 threads, tile 64 rows x 128 cols. Thread (ct=tid&31 -> 4 cols, rt=tid>>5 -> 8 rows).
// LDS A-reads are wave-broadcast (address independent of ct); W loads coalesced 512B/wave.
__global__ __launch_bounds__(256) void k_gemm_scale(
    const float* __restrict__ x, const float* __restrict__ W,
    const float* __restrict__ dis, float* __restrict__ t2, int N) {
  __shared__ float xs[64 * 128];
  const int tid = threadIdx.x;
  const int r0 = blockIdx.x * 64;

  const float4* xg = (const float4*)x;
  float4* xls = (float4*)xs;
#pragma unroll
  for (int j = 0; j < 8; ++j) {
    int s = tid + j * 256;          // float4 slot; row = s>>5, col4 = s&31
    int r = r0 + (s >> 5);
    float4 v = make_float4(0.f, 0.f, 0.f, 0.f);
    if (r < N) v = xg[(size_t)r * 32 + (s & 31)];
    xls[s] = v;
  }
  __syncthreads();

  const int ct = tid & 31;
  const int rt = tid >> 5;
  const int rbase = rt * 8;
  float acc[8][4];
#pragma unroll
  for (int i = 0; i < 8; ++i)
#pragma unroll
    for (int j = 0; j < 4; ++j) acc[i][j] = 0.f;

  const float4* Wg = (const float4*)W;
#pragma unroll 8
  for (int k = 0; k < 128; ++k) {
    float4 b = Wg[k * 32 + ct];
#pragma unroll
    for (int i = 0; i < 8; ++i) {
      float a = xs[(rbase + i) * 128 + k];
      acc[i][0] += a * b.x;
      acc[i][1] += a * b.y;
      acc[i][2] += a * b.z;
      acc[i][3] += a * b.w;
    }
  }

#pragma unroll
  for (int i = 0; i < 8; ++i) {
    int r = r0 + rbase + i;
    if (r < N) {
      float s = dis[r];
      float4 v = make_float4(s * acc[i][0], s * acc[i][1], s * acc[i][2], s * acc[i][3]);
      ((float4*)(t2 + (size_t)r * 128))[ct] = v;
    }
  }
}

__global__ void k_zero4(float4* __restrict__ p, int n4) {
  int i = blockIdx.x * blockDim.x + threadIdx.x;
  if (i < n4) p[i] = make_float4(0.f, 0.f, 0.f, 0.f);
}

// 32 lanes per edge, float4 per lane: out_acc[col] += t2[row]
__global__ void k_scatter(const int* __restrict__ ei, int E,
                          const float* __restrict__ t2, float* __restrict__ acc) {
  int idx = blockIdx.x * blockDim.x + threadIdx.x;
  int e = idx >> 5;
  if (e >= E) return;
  int v = idx & 31;
  int row = ei[e];
  int col = ei[E + e];
  float4 val = ((const float4*)(t2 + (size_t)row * 128))[v];
  float* dst = acc + (size_t)col * 128 + (size_t)v * 4;
  atomicAdd(dst + 0, val.x);
  atomicAdd(dst + 1, val.y);
  atomicAdd(dst + 2, val.z);
  atomicAdd(dst + 3, val.w);
}

// out[i][c] = dis[i] * (acc[i][c] + t2[i][c]) + bias[c]   (in place on out)
__global__ void k_final(float* __restrict__ out, const float* __restrict__ t2,
                        const float* __restrict__ dis, const float* __restrict__ bias, int N) {
  int idx = blockIdx.x * blockDim.x + threadIdx.x;
  if (idx >= N * 32) return;
  int i = idx >> 5;
  int v = idx & 31;
  float4 a = ((float4*)out)[idx];
  float4 t = ((const float4*)t2)[idx];
  float4 b = ((const float4*)bias)[v];
  float s = dis[i];
  float4 r;
  r.x = s * (a.x + t.x) + b.x;
  r.y = s * (a.y + t.y) + b.y;
  r.z = s * (a.z + t.z) + b.z;
  r.w = s * (a.w + t.w) + b.w;
  ((float4*)out)[idx] = r;
}

extern "C" void kernel_launch(void* const* d_in, const int* in_sizes, int n_in,
                              void* d_out, int out_size, void* d_ws, size_t ws_size,
                              hipStream_t stream) {
  const float* x = (const float*)d_in[0];
  const int* ei = (const int*)d_in[1];   // int64 in reference, int32 on device: [2, E] flat
  const float* W = (const float*)d_in[2];
  const float* bias = (const float*)d_in[3];
  float* out = (float*)d_out;

  const int N = in_sizes[0] / 128;
  const int E = in_sizes[1] / 2;

  // workspace layout: t2 [N*128 f32] | dis [N f32] | deg [N i32]  (~26 MB)
  float* t2 = (float*)d_ws;
  float* dis = t2 + (size_t)N * 128;
  int* deg = (int*)(dis + N);

  k_deg_init<<<cdiv(N, 256), 256, 0, stream>>>(deg, N);
  k_deg_count<<<cdiv(E, 256), 256, 0, stream>>>(ei, E, deg);
  k_dis<<<cdiv(N, 256), 256, 0, stream>>>(deg, dis, N);
  k_gemm_scale<<<cdiv(N, 64), 256, 0, stream>>>(x, W, dis, t2, N);
  k_zero4<<<cdiv(N * 32, 256), 256, 0, stream>>>((float4*)out, N * 32);
  k_scatter<<<cdiv(E * 32, 256), 256, 0, stream>>>(ei, E, t2, out);
  k_final<<<cdiv(N * 32, 256), 256, 0, stream>>>(out, t2, dis, bias, N);
}

// Round 3
// 322.290 us; speedup vs baseline: 4.4655x; 4.4655x over previous
//
#include <hip/hip_runtime.h>

// GCN layer on MI355X — CSR-gather formulation (no float atomics).
// out[c] = dis[c] * ( sum_{e: dst=c} t2[src_e] + t2[c] ) + bias
// t2[i] = dis[i] * (x @ W)[i], dis[i] = rsqrt(1 + #occurrences of i in row).
//
// Round-2 post-mortem: atomic scatter wrote 1.6 GB through to coherence point
// (102.4M device-scope fp32 RMWs) -> 1344 us. This version counting-sorts
// edges by destination and accumulates per-node in registers.

static inline int cdiv(int a, int b) { return (a + b - 1) / b; }

__global__ void k_init(int* __restrict__ deg, int* __restrict__ indeg, int n) {
  int i = blockIdx.x * blockDim.x + threadIdx.x;
  if (i < n) { deg[i] = 1; indeg[i] = 0; }  // self loop contributes 1 to deg
}

__global__ void k_count(const int* __restrict__ ei, int E,
                        int* __restrict__ deg, int* __restrict__ indeg) {
  int e = blockIdx.x * blockDim.x + threadIdx.x;
  if (e < E) {
    atomicAdd(&deg[ei[e]], 1);        // row (source) degree -> normalization
    atomicAdd(&indeg[ei[E + e]], 1);  // col (dest) degree -> CSR
  }
}

__global__ void k_dis(const int* __restrict__ deg, float* __restrict__ dis, int n) {
  int i = blockIdx.x * blockDim.x + threadIdx.x;
  if (i < n) dis[i] = rsqrtf((float)deg[i]);
}

// Single-block exclusive scan of indeg[0..N) -> offs[0..N], cursor copy.
__global__ __launch_bounds__(1024) void k_scan(const int* __restrict__ indeg,
                                               int* __restrict__ offs,
                                               int* __restrict__ cursor, int N) {
  __shared__ int tmp[1024];
  __shared__ int carry_s;
  const int tid = threadIdx.x;
  if (tid == 0) carry_s = 0;
  __syncthreads();
  for (int base = 0; base < N; base += 1024) {
    int i = base + tid;
    int v = (i < N) ? indeg[i] : 0;
    tmp[tid] = v;
    __syncthreads();
#pragma unroll
    for (int off = 1; off < 1024; off <<= 1) {
      int add = (tid >= off) ? tmp[tid - off] : 0;
      __syncthreads();
      tmp[tid] += add;
      __syncthreads();
    }
    int incl = tmp[tid];
    int excl = incl - v + carry_s;
    if (i < N) { offs[i] = excl; cursor[i] = excl; }
    __syncthreads();
    if (tid == 1023) carry_s += incl;  // chunk total
    __syncthreads();
  }
  if (tid == 0) offs[N] = carry_s;
}

// Counting-sort placement: srcs[pos] = row, pos = cursor[col]++.
__global__ void k_place(const int* __restrict__ ei, int E,
                        int* __restrict__ cursor, int* __restrict__ srcs) {
  int e = blockIdx.x * blockDim.x + threadIdx.x;
  if (e < E) {
    int col = ei[E + e];
    int pos = atomicAdd(&cursor[col], 1);
    srcs[pos] = ei[e];
  }
}

// t2[r][c] = dis[r] * sum_k x[r][k] * W[k][c]
// Block 256 threads, tile 64 rows x 128 cols.
__global__ __launch_bounds__(256) void k_gemm_scale(
    const float* __restrict__ x, const float* __restrict__ W,
    const float* __restrict__ dis, float* __restrict__ t2, int N) {
  __shared__ float xs[64 * 128];
  const int tid = threadIdx.x;
  const int r0 = blockIdx.x * 64;

  const float4* xg = (const float4*)x;
  float4* xls = (float4*)xs;
#pragma unroll
  for (int j = 0; j < 8; ++j) {
    int s = tid + j * 256;          // float4 slot; row = s>>5, col4 = s&31
    int r = r0 + (s >> 5);
    float4 v = make_float4(0.f, 0.f, 0.f, 0.f);
    if (r < N) v = xg[(size_t)r * 32 + (s & 31)];
    xls[s] = v;
  }
  __syncthreads();

  const int ct = tid & 31;
  const int rt = tid >> 5;
  const int rbase = rt * 8;
  float acc[8][4];
#pragma unroll
  for (int i = 0; i < 8; ++i)
#pragma unroll
    for (int j = 0; j < 4; ++j) acc[i][j] = 0.f;

  const float4* Wg = (const float4*)W;
#pragma unroll 8
  for (int k = 0; k < 128; ++k) {
    float4 b = Wg[k * 32 + ct];
#pragma unroll
    for (int i = 0; i < 8; ++i) {
      float a = xs[(rbase + i) * 128 + k];
      acc[i][0] += a * b.x;
      acc[i][1] += a * b.y;
      acc[i][2] += a * b.z;
      acc[i][3] += a * b.w;
    }
  }

#pragma unroll
  for (int i = 0; i < 8; ++i) {
    int r = r0 + rbase + i;
    if (r < N) {
      float s = dis[r];
      float4 v = make_float4(s * acc[i][0], s * acc[i][1], s * acc[i][2], s * acc[i][3]);
      ((float4*)(t2 + (size_t)r * 128))[ct] = v;
    }
  }
}

// One 64-lane wave per node; lane owns float2 at col=lane*2.
// acc = t2[node] (self loop) + sum over incoming srcs; out = dis*acc + bias.
__global__ __launch_bounds__(256) void k_gather(
    const int* __restrict__ offs, const int* __restrict__ srcs,
    const float* __restrict__ t2, const float* __restrict__ dis,
    const float* __restrict__ bias, float* __restrict__ out, int N) {
  const int node = blockIdx.x * 4 + (threadIdx.x >> 6);
  const int lane = threadIdx.x & 63;
  if (node >= N) return;

  const int s = offs[node];
  const int e = offs[node + 1];
  const size_t c = (size_t)lane * 2;

  float2 acc = *(const float2*)(t2 + (size_t)node * 128 + c);  // self loop
  int j = s;
  for (; j + 1 < e; j += 2) {
    int s0 = srcs[j], s1 = srcs[j + 1];
    float2 v0 = *(const float2*)(t2 + (size_t)s0 * 128 + c);
    float2 v1 = *(const float2*)(t2 + (size_t)s1 * 128 + c);
    acc.x += v0.x + v1.x;
    acc.y += v0.y + v1.y;
  }
  if (j < e) {
    float2 v = *(const float2*)(t2 + (size_t)srcs[j] * 128 + c);
    acc.x += v.x;
    acc.y += v.y;
  }

  const float dn = dis[node];
  const float2 b = *(const float2*)(bias + c);
  float2 r = make_float2(dn * acc.x + b.x, dn * acc.y + b.y);
  *(float2*)(out + (size_t)node * 128 + c) = r;
}

extern "C" void kernel_launch(void* const* d_in, const int* in_sizes, int n_in,
                              void* d_out, int out_size, void* d_ws, size_t ws_size,
                              hipStream_t stream) {
  const float* x = (const float*)d_in[0];
  const int* ei = (const int*)d_in[1];   // int64 in reference, int32 on device: [2,E] flat
  const float* W = (const float*)d_in[2];
  const float* bias = (const float*)d_in[3];
  float* out = (float*)d_out;

  const int N = in_sizes[0] / 128;
  const int E = in_sizes[1] / 2;

  // workspace: t2[N*128 f32] | dis[N f32] | deg[N i32] | indeg[N i32]
  //            | offs[N+1 i32] | cursor[N i32] | srcs[E i32]   (~30 MB)
  float* t2 = (float*)d_ws;
  float* dis = t2 + (size_t)N * 128;
  int* deg = (int*)(dis + N);
  int* indeg = deg + N;
  int* offs = indeg + N;
  int* cursor = offs + (N + 1);
  int* srcs = cursor + N;

  k_init<<<cdiv(N, 256), 256, 0, stream>>>(deg, indeg, N);
  k_count<<<cdiv(E, 256), 256, 0, stream>>>(ei, E, deg, indeg);
  k_dis<<<cdiv(N, 256), 256, 0, stream>>>(deg, dis, N);
  k_scan<<<1, 1024, 0, stream>>>(indeg, offs, cursor, N);
  k_place<<<cdiv(E, 256), 256, 0, stream>>>(ei, E, cursor, srcs);
  k_gemm_scale<<<cdiv(N, 64), 256, 0, stream>>>(x, W, dis, t2, N);
  k_gather<<<cdiv(N, 4), 256, 0, stream>>>(offs, srcs, t2, dis, bias, out, N);
}

// Round 4
// 230.757 us; speedup vs baseline: 6.2369x; 1.3967x over previous
//
#include <hip/hip_runtime.h>

// GCN layer on MI355X — CSR-gather formulation (no float atomics).
// out[c] = dis[c] * ( sum_{e: dst=c} t2[src_e] + t2[c] ) + bias
// t2[i] = dis[i] * (x @ W)[i], dis[i] = rsqrt(1 + #occurrences of i in row).
//
// Round-3 post-mortem: single-block scan was 94 us (29% of total) at 0.18%
// occupancy. Replaced with 3-kernel hierarchical scan (~8 us), dis fused in.

static inline int cdiv(int a, int b) { return (a + b - 1) / b; }

__global__ void k_init(int* __restrict__ deg, int* __restrict__ indeg, int n) {
  int i = blockIdx.x * blockDim.x + threadIdx.x;
  if (i < n) { deg[i] = 1; indeg[i] = 0; }  // self loop contributes 1 to deg
}

__global__ void k_count(const int* __restrict__ ei, int E,
                        int* __restrict__ deg, int* __restrict__ indeg) {
  int e = blockIdx.x * blockDim.x + threadIdx.x;
  if (e < E) {
    atomicAdd(&deg[ei[e]], 1);        // row (source) degree -> normalization
    atomicAdd(&indeg[ei[E + e]], 1);  // col (dest) degree -> CSR
  }
}

// Hierarchical exclusive scan, stage 1: 1024 elems/block (256 thr x 4).
// Writes per-element exclusive-within-block to offs, block total to partials.
__global__ __launch_bounds__(256) void k_scan1(const int* __restrict__ indeg,
                                               int* __restrict__ offs,
                                               int* __restrict__ partials, int N) {
  __shared__ int ws[256];
  const int tid = threadIdx.x;
  const int i0 = blockIdx.x * 1024 + tid * 4;
  int v0 = (i0 + 0 < N) ? indeg[i0 + 0] : 0;
  int v1 = (i0 + 1 < N) ? indeg[i0 + 1] : 0;
  int v2 = (i0 + 2 < N) ? indeg[i0 + 2] : 0;
  int v3 = (i0 + 3 < N) ? indeg[i0 + 3] : 0;
  int tsum = v0 + v1 + v2 + v3;
  ws[tid] = tsum;
  __syncthreads();
#pragma unroll
  for (int off = 1; off < 256; off <<= 1) {
    int add = (tid >= off) ? ws[tid - off] : 0;
    __syncthreads();
    ws[tid] += add;
    __syncthreads();
  }
  int texcl = ws[tid] - tsum;
  if (tid == 255) partials[blockIdx.x] = ws[255];
  if (i0 + 0 < N) offs[i0 + 0] = texcl;
  if (i0 + 1 < N) offs[i0 + 1] = texcl + v0;
  if (i0 + 2 < N) offs[i0 + 2] = texcl + v0 + v1;
  if (i0 + 3 < N) offs[i0 + 3] = texcl + v0 + v1 + v2;
}

// Stage 2: single block scans nb partials in place (exclusive); offs[N] = total.
__global__ __launch_bounds__(256) void k_scan2(int* __restrict__ partials,
                                               int* __restrict__ offs, int N, int nb) {
  __shared__ int ws[256];
  __shared__ int carry_s;
  const int tid = threadIdx.x;
  if (tid == 0) carry_s = 0;
  __syncthreads();
  for (int base = 0; base < nb; base += 256) {
    int i = base + tid;
    int v = (i < nb) ? partials[i] : 0;
    ws[tid] = v;
    __syncthreads();
#pragma unroll
    for (int off = 1; off < 256; off <<= 1) {
      int add = (tid >= off) ? ws[tid - off] : 0;
      __syncthreads();
      ws[tid] += add;
      __syncthreads();
    }
    if (i < nb) partials[i] = ws[tid] - v + carry_s;
    __syncthreads();
    if (tid == 255) carry_s += ws[255];
    __syncthreads();
  }
  if (tid == 0) offs[N] = carry_s;
}

// Stage 3: add block offset; also copy to cursor and compute dis (fused k_dis).
__global__ void k_scan3(int* __restrict__ offs, int* __restrict__ cursor,
                        const int* __restrict__ partials,
                        const int* __restrict__ deg, float* __restrict__ dis, int N) {
  int i = blockIdx.x * blockDim.x + threadIdx.x;
  if (i < N) {
    int v = offs[i] + partials[i >> 10];
    offs[i] = v;
    cursor[i] = v;
    dis[i] = rsqrtf((float)deg[i]);
  }
}

// Counting-sort placement: srcs[pos] = row, pos = cursor[col]++.
__global__ void k_place(const int* __restrict__ ei, int E,
                        int* __restrict__ cursor, int* __restrict__ srcs) {
  int e = blockIdx.x * blockDim.x + threadIdx.x;
  if (e < E) {
    int col = ei[E + e];
    int pos = atomicAdd(&cursor[col], 1);
    srcs[pos] = ei[e];
  }
}

// t2[r][c] = dis[r] * sum_k x[r][k] * W[k][c]
// Block 256 threads, tile 64 rows x 128 cols.
__global__ __launch_bounds__(256) void k_gemm_scale(
    const float* __restrict__ x, const float* __restrict__ W,
    const float* __restrict__ dis, float* __restrict__ t2, int N) {
  __shared__ float xs[64 * 128];
  const int tid = threadIdx.x;
  const int r0 = blockIdx.x * 64;

  const float4* xg = (const float4*)x;
  float4* xls = (float4*)xs;
#pragma unroll
  for (int j = 0; j < 8; ++j) {
    int s = tid + j * 256;          // float4 slot; row = s>>5, col4 = s&31
    int r = r0 + (s >> 5);
    float4 v = make_float4(0.f, 0.f, 0.f, 0.f);
    if (r < N) v = xg[(size_t)r * 32 + (s & 31)];
    xls[s] = v;
  }
  __syncthreads();

  const int ct = tid & 31;
  const int rt = tid >> 5;
  const int rbase = rt * 8;
  float acc[8][4];
#pragma unroll
  for (int i = 0; i < 8; ++i)
#pragma unroll
    for (int j = 0; j < 4; ++j) acc[i][j] = 0.f;

  const float4* Wg = (const float4*)W;
#pragma unroll 8
  for (int k = 0; k < 128; ++k) {
    float4 b = Wg[k * 32 + ct];
#pragma unroll
    for (int i = 0; i < 8; ++i) {
      float a = xs[(rbase + i) * 128 + k];
      acc[i][0] += a * b.x;
      acc[i][1] += a * b.y;
      acc[i][2] += a * b.z;
      acc[i][3] += a * b.w;
    }
  }

#pragma unroll
  for (int i = 0; i < 8; ++i) {
    int r = r0 + rbase + i;
    if (r < N) {
      float s = dis[r];
      float4 v = make_float4(s * acc[i][0], s * acc[i][1], s * acc[i][2], s * acc[i][3]);
      ((float4*)(t2 + (size_t)r * 128))[ct] = v;
    }
  }
}

// One 64-lane wave per node; lane owns float2 at col=lane*2.
// acc = t2[node] (self loop) + sum over incoming srcs; out = dis*acc + bias.
__global__ __launch_bounds__(256) void k_gather(
    const int* __restrict__ offs, const int* __restrict__ srcs,
    const float* __restrict__ t2, const float* __restrict__ dis,
    const float* __restrict__ bias, float* __restrict__ out, int N) {
  const int node = blockIdx.x * 4 + (threadIdx.x >> 6);
  const int lane = threadIdx.x & 63;
  if (node >= N) return;

  const int s = offs[node];
  const int e = offs[node + 1];
  const size_t c = (size_t)lane * 2;

  float2 acc = *(const float2*)(t2 + (size_t)node * 128 + c);  // self loop
  int j = s;
  for (; j + 3 < e; j += 4) {
    int s0 = srcs[j], s1 = srcs[j + 1], s2 = srcs[j + 2], s3 = srcs[j + 3];
    float2 v0 = *(const float2*)(t2 + (size_t)s0 * 128 + c);
    float2 v1 = *(const float2*)(t2 + (size_t)s1 * 128 + c);
    float2 v2 = *(const float2*)(t2 + (size_t)s2 * 128 + c);
    float2 v3 = *(const float2*)(t2 + (size_t)s3 * 128 + c);
    acc.x += (v0.x + v1.x) + (v2.x + v3.x);
    acc.y += (v0.y + v1.y) + (v2.y + v3.y);
  }
  for (; j < e; ++j) {
    float2 v = *(const float2*)(t2 + (size_t)srcs[j] * 128 + c);
    acc.x += v.x;
    acc.y += v.y;
  }

  const float dn = dis[node];
  const float2 b = *(const float2*)(bias + c);
  float2 r = make_float2(dn * acc.x + b.x, dn * acc.y + b.y);
  *(float2*)(out + (size_t)node * 128 + c) = r;
}

extern "C" void kernel_launch(void* const* d_in, const int* in_sizes, int n_in,
                              void* d_out, int out_size, void* d_ws, size_t ws_size,
                              hipStream_t stream) {
  const float* x = (const float*)d_in[0];
  const int* ei = (const int*)d_in[1];   // int64 in reference, int32 on device: [2,E] flat
  const float* W = (const float*)d_in[2];
  const float* bias = (const float*)d_in[3];
  float* out = (float*)d_out;

  const int N = in_sizes[0] / 128;
  const int E = in_sizes[1] / 2;
  const int NB = cdiv(N, 1024);  // scan stage-1 blocks

  // workspace: t2[N*128 f32] | dis[N f32] | deg[N i32] | indeg[N i32]
  //            | offs[N+1 i32] | cursor[N i32] | partials[NB i32] | srcs[E i32]
  float* t2 = (float*)d_ws;
  float* dis = t2 + (size_t)N * 128;
  int* deg = (int*)(dis + N);
  int* indeg = deg + N;
  int* offs = indeg + N;
  int* cursor = offs + (N + 1);
  int* partials = cursor + N;
  int* srcs = partials + NB;

  k_init<<<cdiv(N, 256), 256, 0, stream>>>(deg, indeg, N);
  k_count<<<cdiv(E, 256), 256, 0, stream>>>(ei, E, deg, indeg);
  k_scan1<<<NB, 256, 0, stream>>>(indeg, offs, partials, N);
  k_scan2<<<1, 256, 0, stream>>>(partials, offs, N, NB);
  k_scan3<<<cdiv(N, 256), 256, 0, stream>>>(offs, cursor, partials, deg, dis, N);
  k_place<<<cdiv(E, 256), 256, 0, stream>>>(ei, E, cursor, srcs);
  k_gemm_scale<<<cdiv(N, 64), 256, 0, stream>>>(x, W, dis, t2, N);
  k_gather<<<cdiv(N, 4), 256, 0, stream>>>(offs, srcs, t2, dis, bias, out, N);
}

// Round 5
// 143.044 us; speedup vs baseline: 10.0612x; 1.6132x over previous
//
#include <hip/hip_runtime.h>

// GCN layer on MI355X — CSR-gather with atomic-free CSR build (MSD bucket sort).
// out[c] = dis[c] * ( sum_{e: dst=c} t2[src_e] + t2[c] ) + bias
// t2[i] = dis[i] * (x @ W)[i], dis[i] = rsqrt(1 + #occurrences of i in edge row 0).
//
// Round-4 post-mortem: k_count (65 us) + k_place (~60 us) were bound by random
// device-scope int atomics (~25 ops/ns, 32B coherence transaction each;
// WRITE_SIZE 49.8MB for a 400KB dest). This version builds the CSR with LDS
// histograms + plain global stores only:
//   k_hist: coarse LDS hist of dst>>8 and src>>8, [bin][blk] transposed
//   scan1/2/3: exclusive scan of both hists (concatenated; 2nd half -E)
//   k_part: scatter edges into coarse buckets (LDS cursors, plain stores)
//   k_deg: per-bucket fine count of src -> dis (no deg array)
//   k_csr: per-bucket fine count+scan of dst -> offs, srcs
// Bucket scratch aliases t2 (dead before gemm) -> ws footprint ~29.2 MB.

#define EPB 4096  // edges per k_hist/k_part block

static inline int cdiv(int a, int b) { return (a + b - 1) / b; }

// P1: coarse histograms, transposed layout hist[bin*nblk + blk] (dst) and
// hist[HALF + bin*nblk + blk] (src), HALF = nbins*nblk.
__global__ __launch_bounds__(256) void k_hist(const int* __restrict__ ei, int E,
                                              int* __restrict__ hist, int nblk, int nbins) {
  __shared__ int ha[256], hb[256];
  const int tid = threadIdx.x, blk = blockIdx.x;
  ha[tid] = 0; hb[tid] = 0;
  __syncthreads();
  const int base = blk * EPB;
  for (int i = tid; i < EPB; i += 256) {
    int e = base + i;
    if (e >= E) break;
    int src = ei[e];
    int dst = ei[E + e];
    atomicAdd(&ha[dst >> 8], 1);
    atomicAdd(&hb[src >> 8], 1);
  }
  __syncthreads();
  if (tid < nbins) {
    hist[tid * nblk + blk] = ha[tid];
    hist[nbins * nblk + tid * nblk + blk] = hb[tid];
  }
}

// Hierarchical exclusive scan (in place), 1024 elems/block.
__global__ __launch_bounds__(256) void k_scan1(int* __restrict__ a,
                                               int* __restrict__ partials, int M) {
  __shared__ int ws[256];
  const int tid = threadIdx.x;
  const int i0 = blockIdx.x * 1024 + tid * 4;
  int v0 = (i0 + 0 < M) ? a[i0 + 0] : 0;
  int v1 = (i0 + 1 < M) ? a[i0 + 1] : 0;
  int v2 = (i0 + 2 < M) ? a[i0 + 2] : 0;
  int v3 = (i0 + 3 < M) ? a[i0 + 3] : 0;
  int tsum = v0 + v1 + v2 + v3;
  ws[tid] = tsum;
  __syncthreads();
#pragma unroll
  for (int off = 1; off < 256; off <<= 1) {
    int add = (tid >= off) ? ws[tid - off] : 0;
    __syncthreads();
    ws[tid] += add;
    __syncthreads();
  }
  int texcl = ws[tid] - tsum;
  if (tid == 255) partials[blockIdx.x] = ws[255];
  if (i0 + 0 < M) a[i0 + 0] = texcl;
  if (i0 + 1 < M) a[i0 + 1] = texcl + v0;
  if (i0 + 2 < M) a[i0 + 2] = texcl + v0 + v1;
  if (i0 + 3 < M) a[i0 + 3] = texcl + v0 + v1 + v2;
}

// Stage 2: single block, nb <= 256 partials, exclusive in place.
__global__ __launch_bounds__(256) void k_scan2(int* __restrict__ p, int nb) {
  __shared__ int ws[256];
  const int tid = threadIdx.x;
  int v = (tid < nb) ? p[tid] : 0;
  ws[tid] = v;
  __syncthreads();
#pragma unroll
  for (int off = 1; off < 256; off <<= 1) {
    int add = (tid >= off) ? ws[tid - off] : 0;
    __syncthreads();
    ws[tid] += add;
    __syncthreads();
  }
  if (tid < nb) p[tid] = ws[tid] - v;
}

__global__ void k_scan3(int* __restrict__ a, const int* __restrict__ p, int M) {
  int i = blockIdx.x * blockDim.x + threadIdx.x;
  if (i < M) a[i] += p[i >> 10];
}

// P2: partition edges into coarse buckets. ebA[posA] = (src<<8)|(dst&255)
// (dst-bucketed), ebB[posB] = src&255 (src-bucketed). Plain stores only.
__global__ __launch_bounds__(256) void k_part(const int* __restrict__ ei, int E,
                                              const int* __restrict__ hist,
                                              int nblk, int nbins,
                                              int* __restrict__ ebA, int* __restrict__ ebB) {
  __shared__ int cA[256], cB[256];
  const int tid = threadIdx.x, blk = blockIdx.x;
  const int HALF = nbins * nblk;
  if (tid < nbins) {
    cA[tid] = hist[tid * nblk + blk];
    cB[tid] = hist[HALF + tid * nblk + blk] - E;
  }
  __syncthreads();
  const int base = blk * EPB;
  for (int i = tid; i < EPB; i += 256) {
    int e = base + i;
    if (e >= E) break;
    int src = ei[e];
    int dst = ei[E + e];
    int pa = atomicAdd(&cA[dst >> 8], 1);
    ebA[pa] = (src << 8) | (dst & 255);
    int pb = atomicAdd(&cB[src >> 8], 1);
    ebB[pb] = src & 255;
  }
}

// P3b: per src-bucket fine count -> dis[node] = rsqrt(1 + cnt).
__global__ __launch_bounds__(256) void k_deg(const int* __restrict__ ebB,
                                             const int* __restrict__ hist,
                                             int nblk, int nbins, int E,
                                             float* __restrict__ dis, int N) {
  __shared__ int h[256];
  const int tid = threadIdx.x, b = blockIdx.x;
  const int HALF = nbins * nblk;
  const int bs = hist[HALF + b * nblk] - E;
  const int be = (b + 1 < nbins) ? hist[HALF + (b + 1) * nblk] - E : E;
  h[tid] = 0;
  __syncthreads();
  for (int j = bs + tid; j < be; j += 256) atomicAdd(&h[ebB[j]], 1);
  __syncthreads();
  int node = b * 256 + tid;
  if (node < N) dis[node] = rsqrtf(1.0f + (float)h[tid]);
}

// P3a: per dst-bucket fine count + 256-bin scan -> offs; place srcs.
__global__ __launch_bounds__(256) void k_csr(const int* __restrict__ ebA,
                                             const int* __restrict__ hist,
                                             int nblk, int nbins, int E,
                                             int* __restrict__ offs,
                                             int* __restrict__ srcs, int N) {
  __shared__ int h[256], tmp[256], cur[256];
  const int tid = threadIdx.x, b = blockIdx.x;
  const int bs = hist[b * nblk];
  const int be = (b + 1 < nbins) ? hist[(b + 1) * nblk] : E;
  h[tid] = 0;
  __syncthreads();
  for (int j = bs + tid; j < be; j += 256) atomicAdd(&h[ebA[j] & 255], 1);
  __syncthreads();
  int cnt = h[tid];
  tmp[tid] = cnt;
  __syncthreads();
#pragma unroll
  for (int off = 1; off < 256; off <<= 1) {
    int add = (tid >= off) ? tmp[tid - off] : 0;
    __syncthreads();
    tmp[tid] += add;
    __syncthreads();
  }
  int gpos = bs + tmp[tid] - cnt;
  int node = b * 256 + tid;
  if (node < N) offs[node] = gpos;
  cur[tid] = gpos;
  __syncthreads();
  for (int j = bs + tid; j < be; j += 256) {
    int v = ebA[j];
    int p = atomicAdd(&cur[v & 255], 1);
    srcs[p] = v >> 8;
  }
  if (b == 0 && tid == 0) offs[N] = E;
}

// t2[r][c] = dis[r] * sum_k x[r][k] * W[k][c]
// Block 256 threads, tile 64 rows x 128 cols.
__global__ __launch_bounds__(256) void k_gemm_scale(
    const float* __restrict__ x, const float* __restrict__ W,
    const float* __restrict__ dis, float* __restrict__ t2, int N) {
  __shared__ float xs[64 * 128];
  const int tid = threadIdx.x;
  const int r0 = blockIdx.x * 64;

  const float4* xg = (const float4*)x;
  float4* xls = (float4*)xs;
#pragma unroll
  for (int j = 0; j < 8; ++j) {
    int s = tid + j * 256;          // float4 slot; row = s>>5, col4 = s&31
    int r = r0 + (s >> 5);
    float4 v = make_float4(0.f, 0.f, 0.f, 0.f);
    if (r < N) v = xg[(size_t)r * 32 + (s & 31)];
    xls[s] = v;
  }
  __syncthreads();

  const int ct = tid & 31;
  const int rt = tid >> 5;
  const int rbase = rt * 8;
  float acc[8][4];
#pragma unroll
  for (int i = 0; i < 8; ++i)
#pragma unroll
    for (int j = 0; j < 4; ++j) acc[i][j] = 0.f;

  const float4* Wg = (const float4*)W;
#pragma unroll 8
  for (int k = 0; k < 128; ++k) {
    float4 b = Wg[k * 32 + ct];
#pragma unroll
    for (int i = 0; i < 8; ++i) {
      float a = xs[(rbase + i) * 128 + k];
      acc[i][0] += a * b.x;
      acc[i][1] += a * b.y;
      acc[i][2] += a * b.z;
      acc[i][3] += a * b.w;
    }
  }

#pragma unroll
  for (int i = 0; i < 8; ++i) {
    int r = r0 + rbase + i;
    if (r < N) {
      float s = dis[r];
      float4 v = make_float4(s * acc[i][0], s * acc[i][1], s * acc[i][2], s * acc[i][3]);
      ((float4*)(t2 + (size_t)r * 128))[ct] = v;
    }
  }
}

// One 64-lane wave per node; lane owns float2 at col=lane*2.
__global__ __launch_bounds__(256) void k_gather(
    const int* __restrict__ offs, const int* __restrict__ srcs,
    const float* __restrict__ t2, const float* __restrict__ dis,
    const float* __restrict__ bias, float* __restrict__ out, int N) {
  const int node = blockIdx.x * 4 + (threadIdx.x >> 6);
  const int lane = threadIdx.x & 63;
  if (node >= N) return;

  const int s = offs[node];
  const int e = offs[node + 1];
  const size_t c = (size_t)lane * 2;

  float2 acc = *(const float2*)(t2 + (size_t)node * 128 + c);  // self loop
  int j = s;
  for (; j + 3 < e; j += 4) {
    int s0 = srcs[j], s1 = srcs[j + 1], s2 = srcs[j + 2], s3 = srcs[j + 3];
    float2 v0 = *(const float2*)(t2 + (size_t)s0 * 128 + c);
    float2 v1 = *(const float2*)(t2 + (size_t)s1 * 128 + c);
    float2 v2 = *(const float2*)(t2 + (size_t)s2 * 128 + c);
    float2 v3 = *(const float2*)(t2 + (size_t)s3 * 128 + c);
    acc.x += (v0.x + v1.x) + (v2.x + v3.x);
    acc.y += (v0.y + v1.y) + (v2.y + v3.y);
  }
  for (; j < e; ++j) {
    float2 v = *(const float2*)(t2 + (size_t)srcs[j] * 128 + c);
    acc.x += v.x;
    acc.y += v.y;
  }

  const float dn = dis[node];
  const float2 b = *(const float2*)(bias + c);
  float2 r = make_float2(dn * acc.x + b.x, dn * acc.y + b.y);
  *(float2*)(out + (size_t)node * 128 + c) = r;
}

extern "C" void kernel_launch(void* const* d_in, const int* in_sizes, int n_in,
                              void* d_out, int out_size, void* d_ws, size_t ws_size,
                              hipStream_t stream) {
  const float* x = (const float*)d_in[0];
  const int* ei = (const int*)d_in[1];   // int64 in reference, int32 on device: [2,E] flat
  const float* W = (const float*)d_in[2];
  const float* bias = (const float*)d_in[3];
  float* out = (float*)d_out;

  const int N = in_sizes[0] / 128;
  const int E = in_sizes[1] / 2;
  const int NBLK = cdiv(E, EPB);    // edge blocks (196)
  const int NBINS = cdiv(N, 256);   // coarse node buckets (196)
  const int M = 2 * NBINS * NBLK;   // concatenated hist length
  const int NB1 = cdiv(M, 1024);    // scan stage-1 blocks (<=256 required)

  // Workspace. Overlay region (hist|partials|ebA|ebB ~6.7MB) aliases t2:
  // it is dead before k_gemm_scale writes t2. Total ws use ~29.2 MB.
  float* t2 = (float*)d_ws;
  int* hist = (int*)d_ws;            // [2*NBINS*NBLK]
  int* partials = hist + M;          // [<=256]
  int* ebA = partials + 256;         // [E]  (src<<8)|(dst&255), dst-bucketed
  int* ebB = ebA + E;                // [E]  src&255, src-bucketed
  float* dis = t2 + (size_t)N * 128; // [N]
  int* offs = (int*)(dis + N);       // [N+1]
  int* srcs = offs + (N + 1);        // [E]

  k_hist<<<NBLK, 256, 0, stream>>>(ei, E, hist, NBLK, NBINS);
  k_scan1<<<NB1, 256, 0, stream>>>(hist, partials, M);
  k_scan2<<<1, 256, 0, stream>>>(partials, NB1);
  k_scan3<<<cdiv(M, 256), 256, 0, stream>>>(hist, partials, M);
  k_part<<<NBLK, 256, 0, stream>>>(ei, E, hist, NBLK, NBINS, ebA, ebB);
  k_deg<<<NBINS, 256, 0, stream>>>(ebB, hist, NBLK, NBINS, E, dis, N);
  k_csr<<<NBINS, 256, 0, stream>>>(ebA, hist, NBLK, NBINS, E, offs, srcs, N);
  k_gemm_scale<<<cdiv(N, 64), 256, 0, stream>>>(x, W, dis, t2, N);
  k_gather<<<cdiv(N, 4), 256, 0, stream>>>(offs, srcs, t2, dis, bias, out, N);
}

// Round 6
// 121.597 us; speedup vs baseline: 11.8358x; 1.1764x over previous
//
#include <hip/hip_runtime.h>
#include <hip/hip_fp16.h>

// GCN layer on MI355X — CSR-gather, atomic-free CSR build, fp16 message buffer.
// out[c] = dis[c] * ( sum_{e: dst=c} t2[src_e] + t2[c] ) + bias
// t2[i] = dis[i] * (x @ W)[i], dis[i] = rsqrt(1 + outdeg(i)).
//
// Round-5 post-mortem: k_gather (59us) was L2-miss-BW bound: fp32 t2 = 25.6MB
// vs 8x4MB non-coherent L2s -> FETCH_SIZE 186MB @ 3.65 TB/s. This round:
//  - t2 stored as fp16 (12.8MB): halves gather fetch + gemm writes; precision
//    cost ~1e-4 absmax (fp16 rel err 5e-4, |t2|<~2) vs 3.7e-2 threshold.
//  - k_scan3 deleted: consumers add partials[idx>>10] on the fly.
//  - ebB (src&255, src-bucketed) stored as uchar: 3.2 -> 0.8 MB.

#define EPB 4096  // edges per k_hist/k_part block

static inline int cdiv(int a, int b) { return (a + b - 1) / b; }

// P1: coarse histograms, transposed layout hist[bin*nblk + blk] (dst) and
// hist[HALF + bin*nblk + blk] (src), HALF = nbins*nblk.
__global__ __launch_bounds__(256) void k_hist(const int* __restrict__ ei, int E,
                                              int* __restrict__ hist, int nblk, int nbins) {
  __shared__ int ha[256], hb[256];
  const int tid = threadIdx.x, blk = blockIdx.x;
  ha[tid] = 0; hb[tid] = 0;
  __syncthreads();
  const int base = blk * EPB;
  for (int i = tid; i < EPB; i += 256) {
    int e = base + i;
    if (e >= E) break;
    int src = ei[e];
    int dst = ei[E + e];
    atomicAdd(&ha[dst >> 8], 1);
    atomicAdd(&hb[src >> 8], 1);
  }
  __syncthreads();
  if (tid < nbins) {
    hist[tid * nblk + blk] = ha[tid];
    hist[nbins * nblk + tid * nblk + blk] = hb[tid];
  }
}

// Hierarchical exclusive scan stage 1 (in place), 1024 elems/block.
// Consumers add partials[idx>>10]; no stage-3 pass.
__global__ __launch_bounds__(256) void k_scan1(int* __restrict__ a,
                                               int* __restrict__ partials, int M) {
  __shared__ int ws[256];
  const int tid = threadIdx.x;
  const int i0 = blockIdx.x * 1024 + tid * 4;
  int v0 = (i0 + 0 < M) ? a[i0 + 0] : 0;
  int v1 = (i0 + 1 < M) ? a[i0 + 1] : 0;
  int v2 = (i0 + 2 < M) ? a[i0 + 2] : 0;
  int v3 = (i0 + 3 < M) ? a[i0 + 3] : 0;
  int tsum = v0 + v1 + v2 + v3;
  ws[tid] = tsum;
  __syncthreads();
#pragma unroll
  for (int off = 1; off < 256; off <<= 1) {
    int add = (tid >= off) ? ws[tid - off] : 0;
    __syncthreads();
    ws[tid] += add;
    __syncthreads();
  }
  int texcl = ws[tid] - tsum;
  if (tid == 255) partials[blockIdx.x] = ws[255];
  if (i0 + 0 < M) a[i0 + 0] = texcl;
  if (i0 + 1 < M) a[i0 + 1] = texcl + v0;
  if (i0 + 2 < M) a[i0 + 2] = texcl + v0 + v1;
  if (i0 + 3 < M) a[i0 + 3] = texcl + v0 + v1 + v2;
}

// Stage 2: single block, nb <= 256 partials, exclusive in place.
__global__ __launch_bounds__(256) void k_scan2(int* __restrict__ p, int nb) {
  __shared__ int ws[256];
  const int tid = threadIdx.x;
  int v = (tid < nb) ? p[tid] : 0;
  ws[tid] = v;
  __syncthreads();
#pragma unroll
  for (int off = 1; off < 256; off <<= 1) {
    int add = (tid >= off) ? ws[tid - off] : 0;
    __syncthreads();
    ws[tid] += add;
    __syncthreads();
  }
  if (tid < nb) p[tid] = ws[tid] - v;
}

// P2: partition edges into coarse buckets. ebA[posA] = (src<<8)|(dst&255)
// (dst-bucketed), ebB[posB] = src&255 (src-bucketed, uchar). Plain stores only.
__global__ __launch_bounds__(256) void k_part(const int* __restrict__ ei, int E,
                                              const int* __restrict__ hist,
                                              const int* __restrict__ partials,
                                              int nblk, int nbins,
                                              int* __restrict__ ebA,
                                              unsigned char* __restrict__ ebB) {
  __shared__ int cA[256], cB[256];
  const int tid = threadIdx.x, blk = blockIdx.x;
  const int HALF = nbins * nblk;
  if (tid < nbins) {
    int ia = tid * nblk + blk;
    int ib = HALF + tid * nblk + blk;
    cA[tid] = hist[ia] + partials[ia >> 10];
    cB[tid] = hist[ib] + partials[ib >> 10] - E;
  }
  __syncthreads();
  const int base = blk * EPB;
  for (int i = tid; i < EPB; i += 256) {
    int e = base + i;
    if (e >= E) break;
    int src = ei[e];
    int dst = ei[E + e];
    int pa = atomicAdd(&cA[dst >> 8], 1);
    ebA[pa] = (src << 8) | (dst & 255);
    int pb = atomicAdd(&cB[src >> 8], 1);
    ebB[pb] = (unsigned char)(src & 255);
  }
}

// P3b: per src-bucket fine count -> dis[node] = rsqrt(1 + cnt).
__global__ __launch_bounds__(256) void k_deg(const unsigned char* __restrict__ ebB,
                                             const int* __restrict__ hist,
                                             const int* __restrict__ partials,
                                             int nblk, int nbins, int E,
                                             float* __restrict__ dis, int N) {
  __shared__ int h[256];
  const int tid = threadIdx.x, b = blockIdx.x;
  const int HALF = nbins * nblk;
  int i0 = HALF + b * nblk;
  const int bs = hist[i0] + partials[i0 >> 10] - E;
  int be = E;
  if (b + 1 < nbins) {
    int i1 = HALF + (b + 1) * nblk;
    be = hist[i1] + partials[i1 >> 10] - E;
  }
  h[tid] = 0;
  __syncthreads();
  for (int j = bs + tid; j < be; j += 256) atomicAdd(&h[ebB[j]], 1);
  __syncthreads();
  int node = b * 256 + tid;
  if (node < N) dis[node] = rsqrtf(1.0f + (float)h[tid]);
}

// P3a: per dst-bucket fine count + 256-bin scan -> offs; place srcs.
__global__ __launch_bounds__(256) void k_csr(const int* __restrict__ ebA,
                                             const int* __restrict__ hist,
                                             const int* __restrict__ partials,
                                             int nblk, int nbins, int E,
                                             int* __restrict__ offs,
                                             int* __restrict__ srcs, int N) {
  __shared__ int h[256], tmp[256], cur[256];
  const int tid = threadIdx.x, b = blockIdx.x;
  int i0 = b * nblk;
  const int bs = hist[i0] + partials[i0 >> 10];
  int be = E;
  if (b + 1 < nbins) {
    int i1 = (b + 1) * nblk;
    be = hist[i1] + partials[i1 >> 10];
  }
  h[tid] = 0;
  __syncthreads();
  for (int j = bs + tid; j < be; j += 256) atomicAdd(&h[ebA[j] & 255], 1);
  __syncthreads();
  int cnt = h[tid];
  tmp[tid] = cnt;
  __syncthreads();
#pragma unroll
  for (int off = 1; off < 256; off <<= 1) {
    int add = (tid >= off) ? tmp[tid - off] : 0;
    __syncthreads();
    tmp[tid] += add;
    __syncthreads();
  }
  int gpos = bs + tmp[tid] - cnt;
  int node = b * 256 + tid;
  if (node < N) offs[node] = gpos;
  cur[tid] = gpos;
  __syncthreads();
  for (int j = bs + tid; j < be; j += 256) {
    int v = ebA[j];
    int p = atomicAdd(&cur[v & 255], 1);
    srcs[p] = v >> 8;
  }
  if (b == 0 && tid == 0) offs[N] = E;
}

// t2h[r][c] = fp16( dis[r] * sum_k x[r][k] * W[k][c] )
// Block 256 threads, tile 64 rows x 128 cols.
__global__ __launch_bounds__(256) void k_gemm_scale(
    const float* __restrict__ x, const float* __restrict__ W,
    const float* __restrict__ dis, __half* __restrict__ t2h, int N) {
  __shared__ float xs[64 * 128];
  const int tid = threadIdx.x;
  const int r0 = blockIdx.x * 64;

  const float4* xg = (const float4*)x;
  float4* xls = (float4*)xs;
#pragma unroll
  for (int j = 0; j < 8; ++j) {
    int s = tid + j * 256;          // float4 slot; row = s>>5, col4 = s&31
    int r = r0 + (s >> 5);
    float4 v = make_float4(0.f, 0.f, 0.f, 0.f);
    if (r < N) v = xg[(size_t)r * 32 + (s & 31)];
    xls[s] = v;
  }
  __syncthreads();

  const int ct = tid & 31;
  const int rt = tid >> 5;
  const int rbase = rt * 8;
  float acc[8][4];
#pragma unroll
  for (int i = 0; i < 8; ++i)
#pragma unroll
    for (int j = 0; j < 4; ++j) acc[i][j] = 0.f;

  const float4* Wg = (const float4*)W;
#pragma unroll 8
  for (int k = 0; k < 128; ++k) {
    float4 b = Wg[k * 32 + ct];
#pragma unroll
    for (int i = 0; i < 8; ++i) {
      float a = xs[(rbase + i) * 128 + k];
      acc[i][0] += a * b.x;
      acc[i][1] += a * b.y;
      acc[i][2] += a * b.z;
      acc[i][3] += a * b.w;
    }
  }

#pragma unroll
  for (int i = 0; i < 8; ++i) {
    int r = r0 + rbase + i;
    if (r < N) {
      float s = dis[r];
      __half2 h0 = __floats2half2_rn(s * acc[i][0], s * acc[i][1]);
      __half2 h1 = __floats2half2_rn(s * acc[i][2], s * acc[i][3]);
      __half2* rowp = (__half2*)(t2h + (size_t)r * 128);
      rowp[2 * ct + 0] = h0;
      rowp[2 * ct + 1] = h1;
    }
  }
}

// One 64-lane wave per node; lane owns __half2 at col=lane*2 (4B/lane, 256B/row).
__global__ __launch_bounds__(256) void k_gather(
    const int* __restrict__ offs, const int* __restrict__ srcs,
    const __half* __restrict__ t2h, const float* __restrict__ dis,
    const float* __restrict__ bias, float* __restrict__ out, int N) {
  const int node = blockIdx.x * 4 + (threadIdx.x >> 6);
  const int lane = threadIdx.x & 63;
  if (node >= N) return;

  const int s = offs[node];
  const int e = offs[node + 1];
  const __half2* t2h2 = (const __half2*)t2h;

  float2 acc = __half22float2(t2h2[(size_t)node * 64 + lane]);  // self loop
  int j = s;
  for (; j + 3 < e; j += 4) {
    int s0 = srcs[j], s1 = srcs[j + 1], s2 = srcs[j + 2], s3 = srcs[j + 3];
    float2 v0 = __half22float2(t2h2[(size_t)s0 * 64 + lane]);
    float2 v1 = __half22float2(t2h2[(size_t)s1 * 64 + lane]);
    float2 v2 = __half22float2(t2h2[(size_t)s2 * 64 + lane]);
    float2 v3 = __half22float2(t2h2[(size_t)s3 * 64 + lane]);
    acc.x += (v0.x + v1.x) + (v2.x + v3.x);
    acc.y += (v0.y + v1.y) + (v2.y + v3.y);
  }
  for (; j < e; ++j) {
    float2 v = __half22float2(t2h2[(size_t)srcs[j] * 64 + lane]);
    acc.x += v.x;
    acc.y += v.y;
  }

  const float dn = dis[node];
  const float2 b = *(const float2*)(bias + (size_t)lane * 2);
  float2 r = make_float2(dn * acc.x + b.x, dn * acc.y + b.y);
  *(float2*)(out + (size_t)node * 128 + (size_t)lane * 2) = r;
}

extern "C" void kernel_launch(void* const* d_in, const int* in_sizes, int n_in,
                              void* d_out, int out_size, void* d_ws, size_t ws_size,
                              hipStream_t stream) {
  const float* x = (const float*)d_in[0];
  const int* ei = (const int*)d_in[1];   // int64 in reference, int32 on device: [2,E] flat
  const float* W = (const float*)d_in[2];
  const float* bias = (const float*)d_in[3];
  float* out = (float*)d_out;

  const int N = in_sizes[0] / 128;
  const int E = in_sizes[1] / 2;
  const int NBLK = cdiv(E, EPB);    // edge blocks (196)
  const int NBINS = cdiv(N, 256);   // coarse node buckets (196)
  const int M = 2 * NBINS * NBLK;   // concatenated hist length
  const int NB1 = cdiv(M, 1024);    // scan stage-1 blocks (<=256 required)

  // Workspace. Overlay region (hist|partials|ebA|ebB ~4.4MB) aliases t2h
  // (12.8MB): dead before k_gemm_scale writes t2h. Total ws use ~16.4 MB.
  __half* t2h = (__half*)d_ws;
  int* hist = (int*)d_ws;                      // [M]
  int* partials = hist + M;                    // [<=256]
  int* ebA = partials + 256;                   // [E]  (src<<8)|(dst&255), dst-bucketed
  unsigned char* ebB = (unsigned char*)(ebA + E);  // [E] src&255, src-bucketed
  float* dis = (float*)(t2h + (size_t)N * 128);    // [N]
  int* offs = (int*)(dis + N);                 // [N+1]
  int* srcs = offs + (N + 1);                  // [E]

  k_hist<<<NBLK, 256, 0, stream>>>(ei, E, hist, NBLK, NBINS);
  k_scan1<<<NB1, 256, 0, stream>>>(hist, partials, M);
  k_scan2<<<1, 256, 0, stream>>>(partials, NB1);
  k_part<<<NBLK, 256, 0, stream>>>(ei, E, hist, partials, NBLK, NBINS, ebA, ebB);
  k_deg<<<NBINS, 256, 0, stream>>>(ebB, hist, partials, NBLK, NBINS, E, dis, N);
  k_csr<<<NBINS, 256, 0, stream>>>(ebA, hist, partials, NBLK, NBINS, E, offs, srcs, N);
  k_gemm_scale<<<cdiv(N, 64), 256, 0, stream>>>(x, W, dis, t2h, N);
  k_gather<<<cdiv(N, 4), 256, 0, stream>>>(offs, srcs, t2h, dis, bias, out, N);
}

// Round 7
// 111.989 us; speedup vs baseline: 12.8512x; 1.0858x over previous
//
#include <hip/hip_runtime.h>
#include <hip/hip_fp16.h>

// GCN layer on MI355X — CSR-gather, atomic-free CSR build, fp16 MFMA GEMM.
// out[c] = dis[c] * ( sum_{e: dst=c} t2[src_e] + t2[c] ) + bias
// t2[i] = dis[i] * (x @ W)[i], dis[i] = rsqrt(1 + outdeg(i)).
//
// Round-6 post-mortem: fp32 vector-ALU gemm was 46us (latency-bound: VALUBusy
// 27%, occ 29%, 4.4x the 10.4us fp32-vector floor). t2 is consumed at fp16
// anyway, so compute x@W on the matrix cores in fp16 (fp32 accumulate):
// 8x mfma_f32_16x16x32_f16 tiles x 4 k-chunks per wave, A straight from
// global (coalesced, read-once), B from a pre-transposed fp16 WhT[col][k]
// (32KB, L2-hot), epilogue via per-wave LDS transpose -> 16B stores.

#define EPB 4096  // edges per k_hist/k_part block

typedef _Float16 f16;
typedef f16 f16x8 __attribute__((ext_vector_type(8)));
typedef float f32x4 __attribute__((ext_vector_type(4)));

static inline int cdiv(int a, int b) { return (a + b - 1) / b; }

// P1: coarse histograms, transposed layout hist[bin*nblk + blk] (dst) and
// hist[HALF + bin*nblk + blk] (src), HALF = nbins*nblk.
__global__ __launch_bounds__(256) void k_hist(const int* __restrict__ ei, int E,
                                              int* __restrict__ hist, int nblk, int nbins) {
  __shared__ int ha[256], hb[256];
  const int tid = threadIdx.x, blk = blockIdx.x;
  ha[tid] = 0; hb[tid] = 0;
  __syncthreads();
  const int base = blk * EPB;
  for (int i = tid; i < EPB; i += 256) {
    int e = base + i;
    if (e >= E) break;
    int src = ei[e];
    int dst = ei[E + e];
    atomicAdd(&ha[dst >> 8], 1);
    atomicAdd(&hb[src >> 8], 1);
  }
  __syncthreads();
  if (tid < nbins) {
    hist[tid * nblk + blk] = ha[tid];
    hist[nbins * nblk + tid * nblk + blk] = hb[tid];
  }
}

// Hierarchical exclusive scan stage 1 (in place), 1024 elems/block.
// Consumers add partials[idx>>10]; no stage-3 pass.
__global__ __launch_bounds__(256) void k_scan1(int* __restrict__ a,
                                               int* __restrict__ partials, int M) {
  __shared__ int ws[256];
  const int tid = threadIdx.x;
  const int i0 = blockIdx.x * 1024 + tid * 4;
  int v0 = (i0 + 0 < M) ? a[i0 + 0] : 0;
  int v1 = (i0 + 1 < M) ? a[i0 + 1] : 0;
  int v2 = (i0 + 2 < M) ? a[i0 + 2] : 0;
  int v3 = (i0 + 3 < M) ? a[i0 + 3] : 0;
  int tsum = v0 + v1 + v2 + v3;
  ws[tid] = tsum;
  __syncthreads();
#pragma unroll
  for (int off = 1; off < 256; off <<= 1) {
    int add = (tid >= off) ? ws[tid - off] : 0;
    __syncthreads();
    ws[tid] += add;
    __syncthreads();
  }
  int texcl = ws[tid] - tsum;
  if (tid == 255) partials[blockIdx.x] = ws[255];
  if (i0 + 0 < M) a[i0 + 0] = texcl;
  if (i0 + 1 < M) a[i0 + 1] = texcl + v0;
  if (i0 + 2 < M) a[i0 + 2] = texcl + v0 + v1;
  if (i0 + 3 < M) a[i0 + 3] = texcl + v0 + v1 + v2;
}

// Stage 2: single block, nb <= 256 partials, exclusive in place.
__global__ __launch_bounds__(256) void k_scan2(int* __restrict__ p, int nb) {
  __shared__ int ws[256];
  const int tid = threadIdx.x;
  int v = (tid < nb) ? p[tid] : 0;
  ws[tid] = v;
  __syncthreads();
#pragma unroll
  for (int off = 1; off < 256; off <<= 1) {
    int add = (tid >= off) ? ws[tid - off] : 0;
    __syncthreads();
    ws[tid] += add;
    __syncthreads();
  }
  if (tid < nb) p[tid] = ws[tid] - v;
}

// W[k][c] fp32 -> WhT[c][k] fp16 (B^T layout for the MFMA B-operand).
__global__ __launch_bounds__(256) void k_wt(const float* __restrict__ W,
                                            f16* __restrict__ WhT) {
  int gid = blockIdx.x * 256 + threadIdx.x;  // gid = k*128 + c
  int k = gid >> 7, c = gid & 127;
  WhT[c * 128 + k] = (f16)W[gid];
}

// P2: partition edges into coarse buckets. ebA[posA] = (src<<8)|(dst&255)
// (dst-bucketed), ebB[posB] = src&255 (src-bucketed, uchar). Plain stores only.
__global__ __launch_bounds__(256) void k_part(const int* __restrict__ ei, int E,
                                              const int* __restrict__ hist,
                                              const int* __restrict__ partials,
                                              int nblk, int nbins,
                                              int* __restrict__ ebA,
                                              unsigned char* __restrict__ ebB) {
  __shared__ int cA[256], cB[256];
  const int tid = threadIdx.x, blk = blockIdx.x;
  const int HALF = nbins * nblk;
  if (tid < nbins) {
    int ia = tid * nblk + blk;
    int ib = HALF + tid * nblk + blk;
    cA[tid] = hist[ia] + partials[ia >> 10];
    cB[tid] = hist[ib] + partials[ib >> 10] - E;
  }
  __syncthreads();
  const int base = blk * EPB;
  for (int i = tid; i < EPB; i += 256) {
    int e = base + i;
    if (e >= E) break;
    int src = ei[e];
    int dst = ei[E + e];
    int pa = atomicAdd(&cA[dst >> 8], 1);
    ebA[pa] = (src << 8) | (dst & 255);
    int pb = atomicAdd(&cB[src >> 8], 1);
    ebB[pb] = (unsigned char)(src & 255);
  }
}

// P3b: per src-bucket fine count -> dis[node] = rsqrt(1 + cnt).
__global__ __launch_bounds__(256) void k_deg(const unsigned char* __restrict__ ebB,
                                             const int* __restrict__ hist,
                                             const int* __restrict__ partials,
                                             int nblk, int nbins, int E,
                                             float* __restrict__ dis, int N) {
  __shared__ int h[256];
  const int tid = threadIdx.x, b = blockIdx.x;
  const int HALF = nbins * nblk;
  int i0 = HALF + b * nblk;
  const int bs = hist[i0] + partials[i0 >> 10] - E;
  int be = E;
  if (b + 1 < nbins) {
    int i1 = HALF + (b + 1) * nblk;
    be = hist[i1] + partials[i1 >> 10] - E;
  }
  h[tid] = 0;
  __syncthreads();
  for (int j = bs + tid; j < be; j += 256) atomicAdd(&h[ebB[j]], 1);
  __syncthreads();
  int node = b * 256 + tid;
  if (node < N) dis[node] = rsqrtf(1.0f + (float)h[tid]);
}

// P3a: per dst-bucket fine count + 256-bin scan -> offs; place srcs.
__global__ __launch_bounds__(256) void k_csr(const int* __restrict__ ebA,
                                             const int* __restrict__ hist,
                                             const int* __restrict__ partials,
                                             int nblk, int nbins, int E,
                                             int* __restrict__ offs,
                                             int* __restrict__ srcs, int N) {
  __shared__ int h[256], tmp[256], cur[256];
  const int tid = threadIdx.x, b = blockIdx.x;
  int i0 = b * nblk;
  const int bs = hist[i0] + partials[i0 >> 10];
  int be = E;
  if (b + 1 < nbins) {
    int i1 = (b + 1) * nblk;
    be = hist[i1] + partials[i1 >> 10];
  }
  h[tid] = 0;
  __syncthreads();
  for (int j = bs + tid; j < be; j += 256) atomicAdd(&h[ebA[j] & 255], 1);
  __syncthreads();
  int cnt = h[tid];
  tmp[tid] = cnt;
  __syncthreads();
#pragma unroll
  for (int off = 1; off < 256; off <<= 1) {
    int add = (tid >= off) ? tmp[tid - off] : 0;
    __syncthreads();
    tmp[tid] += add;
    __syncthreads();
  }
  int gpos = bs + tmp[tid] - cnt;
  int node = b * 256 + tid;
  if (node < N) offs[node] = gpos;
  cur[tid] = gpos;
  __syncthreads();
  for (int j = bs + tid; j < be; j += 256) {
    int v = ebA[j];
    int p = atomicAdd(&cur[v & 255], 1);
    srcs[p] = v >> 8;
  }
  if (b == 0 && tid == 0) offs[N] = E;
}

// MFMA GEMM: t2h[r][c] = fp16( dis[r] * sum_k x[r][k] * W[k][c] ).
// 256 thr = 4 waves; wave w owns rows [blk*64 + w*16, +16), all 128 cols.
// Per wave: 8 col-tiles x 4 k-chunks of mfma_f32_16x16x32_f16.
// A fragment: lane l reads x[row = l&15][k0 = kc*32+(l>>4)*8 .. +8] (fp32->f16).
// B fragment: lane l reads WhT[col = l&15 (+ct*16)][k0 .. +8] (16B load).
// C/D layout: col = lane&15, row = (lane>>4)*4 + reg  [guide §3, m89].
__global__ __launch_bounds__(256) void k_gemm_mfma(
    const float* __restrict__ x, const f16* __restrict__ WhT,
    const float* __restrict__ dis, __half* __restrict__ t2h, int N) {
  __shared__ __align__(16) f16 cs[4][16][136];  // stride 272B = 17x16B
  const int tid = threadIdx.x;
  const int w = tid >> 6, l = tid & 63;
  const int l15 = l & 15, lg = l >> 4;
  const int wr0 = blockIdx.x * 64 + w * 16;
  const int arow = wr0 + l15;
  const bool avalid = arow < N;

  f32x4 acc[8];
#pragma unroll
  for (int ct = 0; ct < 8; ++ct) acc[ct] = (f32x4){0.f, 0.f, 0.f, 0.f};

#pragma unroll
  for (int kc = 0; kc < 4; ++kc) {
    f16x8 af;
    if (avalid) {
      const float4* ap = (const float4*)(x + (size_t)arow * 128 + kc * 32 + lg * 8);
      float4 a0 = ap[0], a1 = ap[1];
      af[0] = (f16)a0.x; af[1] = (f16)a0.y; af[2] = (f16)a0.z; af[3] = (f16)a0.w;
      af[4] = (f16)a1.x; af[5] = (f16)a1.y; af[6] = (f16)a1.z; af[7] = (f16)a1.w;
    } else {
#pragma unroll
      for (int j = 0; j < 8; ++j) af[j] = (f16)0.f;
    }
#pragma unroll
    for (int ct = 0; ct < 8; ++ct) {
      f16x8 bf = *(const f16x8*)(WhT + (ct * 16 + l15) * 128 + kc * 32 + lg * 8);
      acc[ct] = __builtin_amdgcn_mfma_f32_16x16x32_f16(af, bf, acc[ct], 0, 0, 0);
    }
  }

  // scale rows by dis and stash (transposed per-wave) in LDS
  float d4[4];
#pragma unroll
  for (int j = 0; j < 4; ++j) {
    int r = wr0 + lg * 4 + j;
    d4[j] = (r < N) ? dis[r] : 0.f;
  }
#pragma unroll
  for (int ct = 0; ct < 8; ++ct)
#pragma unroll
    for (int j = 0; j < 4; ++j)
      cs[w][lg * 4 + j][ct * 16 + l15] = (f16)(d4[j] * acc[ct][j]);
  __syncthreads();

  // coalesced write-out: 4 iters x 64 lanes x 16B
#pragma unroll
  for (int it = 0; it < 4; ++it) {
    int t = it * 64 + l;
    int row = t >> 4, seg = t & 15;
    int gr = wr0 + row;
    if (gr < N)
      *(f16x8*)((f16*)t2h + (size_t)gr * 128 + seg * 8) = *(const f16x8*)&cs[w][row][seg * 8];
  }
}

// One 64-lane wave per node; lane owns __half2 at col=lane*2 (4B/lane, 256B/row).
__global__ __launch_bounds__(256) void k_gather(
    const int* __restrict__ offs, const int* __restrict__ srcs,
    const __half* __restrict__ t2h, const float* __restrict__ dis,
    const float* __restrict__ bias, float* __restrict__ out, int N) {
  const int node = blockIdx.x * 4 + (threadIdx.x >> 6);
  const int lane = threadIdx.x & 63;
  if (node >= N) return;

  const int s = offs[node];
  const int e = offs[node + 1];
  const __half2* t2h2 = (const __half2*)t2h;

  float2 acc = __half22float2(t2h2[(size_t)node * 64 + lane]);  // self loop
  int j = s;
  for (; j + 3 < e; j += 4) {
    int s0 = srcs[j], s1 = srcs[j + 1], s2 = srcs[j + 2], s3 = srcs[j + 3];
    float2 v0 = __half22float2(t2h2[(size_t)s0 * 64 + lane]);
    float2 v1 = __half22float2(t2h2[(size_t)s1 * 64 + lane]);
    float2 v2 = __half22float2(t2h2[(size_t)s2 * 64 + lane]);
    float2 v3 = __half22float2(t2h2[(size_t)s3 * 64 + lane]);
    acc.x += (v0.x + v1.x) + (v2.x + v3.x);
    acc.y += (v0.y + v1.y) + (v2.y + v3.y);
  }
  for (; j < e; ++j) {
    float2 v = __half22float2(t2h2[(size_t)srcs[j] * 64 + lane]);
    acc.x += v.x;
    acc.y += v.y;
  }

  const float dn = dis[node];
  const float2 b = *(const float2*)(bias + (size_t)lane * 2);
  float2 r = make_float2(dn * acc.x + b.x, dn * acc.y + b.y);
  *(float2*)(out + (size_t)node * 128 + (size_t)lane * 2) = r;
}

extern "C" void kernel_launch(void* const* d_in, const int* in_sizes, int n_in,
                              void* d_out, int out_size, void* d_ws, size_t ws_size,
                              hipStream_t stream) {
  const float* x = (const float*)d_in[0];
  const int* ei = (const int*)d_in[1];   // int64 in reference, int32 on device: [2,E] flat
  const float* W = (const float*)d_in[2];
  const float* bias = (const float*)d_in[3];
  float* out = (float*)d_out;

  const int N = in_sizes[0] / 128;
  const int E = in_sizes[1] / 2;
  const int NBLK = cdiv(E, EPB);    // edge blocks (196)
  const int NBINS = cdiv(N, 256);   // coarse node buckets (196)
  const int M = 2 * NBINS * NBLK;   // concatenated hist length
  const int NB1 = cdiv(M, 1024);    // scan stage-1 blocks (<=256 required)

  // Workspace. Overlay region (hist|partials|ebA|ebB ~4.4MB) aliases t2h
  // (12.8MB): dead before k_gemm_mfma writes t2h. Total ws use ~16.5 MB.
  __half* t2h = (__half*)d_ws;
  int* hist = (int*)d_ws;                      // [M]
  int* partials = hist + M;                    // [<=256]
  int* ebA = partials + 256;                   // [E]  (src<<8)|(dst&255), dst-bucketed
  unsigned char* ebB = (unsigned char*)(ebA + E);  // [E] src&255, src-bucketed
  float* dis = (float*)(t2h + (size_t)N * 128);    // [N]
  int* offs = (int*)(dis + N);                 // [N+1]
  int* srcs = offs + (N + 1);                  // [E]
  f16* WhT = (f16*)(srcs + E);                 // [128*128] fp16 B^T

  k_hist<<<NBLK, 256, 0, stream>>>(ei, E, hist, NBLK, NBINS);
  k_scan1<<<NB1, 256, 0, stream>>>(hist, partials, M);
  k_scan2<<<1, 256, 0, stream>>>(partials, NB1);
  k_wt<<<64, 256, 0, stream>>>(W, WhT);
  k_part<<<NBLK, 256, 0, stream>>>(ei, E, hist, partials, NBLK, NBINS, ebA, ebB);
  k_deg<<<NBINS, 256, 0, stream>>>(ebB, hist, partials, NBLK, NBINS, E, dis, N);
  k_csr<<<NBINS, 256, 0, stream>>>(ebA, hist, partials, NBLK, NBINS, E, offs, srcs, N);
  k_gemm_mfma<<<cdiv(N, 64), 256, 0, stream>>>(x, WhT, dis, t2h, N);
  k_gather<<<cdiv(N, 4), 256, 0, stream>>>(offs, srcs, t2h, dis, bias, out, N);
}